// Round 4
// baseline (213.700 us; speedup 1.0000x reference)
//
#include <hip/hip_runtime.h>

// VectorQuantizer: x [16,1024,256] f32, E [8192,256] f32.
// Outputs concat: quantized_st (4194304 f32) | loss (1) | perplexity (1).
//
// Round 4:
//  - score_argmin split-K: 512 blocks = 256 row-blocks x 2 code-halves ->
//    2 blocks/CU = 2 waves/SIMD, so wave A's MFMA overlaps wave B's VALU
//    epilogue + load waits (round 3: 1 wave/SIMD, MfmaUtil 30% ~ VALUBusy 29%
//    serialized). Per-row result packed as (orderable_f32(score)<<32 | idx)
//    u64; consumers take min of the two halves (tie -> lower idx).
//  - no global counts / no memset dispatch: pack_e zeroes loss_sum; finalize
//    builds an LDS histogram from best64.

#define VQ_N 16384
#define VQ_D 256
#define VQ_K 8192

typedef __attribute__((ext_vector_type(8))) short short8;   // 8 bf16
typedef __attribute__((ext_vector_type(4))) float f32x4;

__device__ inline unsigned short f2bf(float f) {  // RNE f32 -> bf16 bits
  unsigned int u = __float_as_uint(f);
  return (unsigned short)((u + 0x7fffu + ((u >> 16) & 1u)) >> 16);
}

__device__ inline unsigned int orderable(float s) {
  const unsigned int u = __float_as_uint(s);
  return ((int)u < 0) ? ~u : (u | 0x80000000u);
}

// ---- pack E -> bf16 swizzled + enorm (fused); also zeroes loss_sum ----
// Swizzle: 16B block at ((c*32 + g)*32 + kl)*16 bytes; c=k>>5, g=dim/8, kl=k&31.
__global__ __launch_bounds__(256) void vq_pack_e(
    const float* __restrict__ E, unsigned short* __restrict__ Ebs,
    float* __restrict__ enorm, double* __restrict__ loss_sum) {
  const int gid = blockIdx.x * 256 + threadIdx.x;  // 0..262143
  if (gid == 0) *loss_sum = 0.0;
  const int k = gid >> 5;
  const int g = gid & 31;
  const float* src = E + (size_t)k * VQ_D + g * 8;
  const float4 a = *(const float4*)src;
  const float4 b = *(const float4*)(src + 4);
  uint4 o;
  o.x = (unsigned)f2bf(a.x) | ((unsigned)f2bf(a.y) << 16);
  o.y = (unsigned)f2bf(a.z) | ((unsigned)f2bf(a.w) << 16);
  o.z = (unsigned)f2bf(b.x) | ((unsigned)f2bf(b.y) << 16);
  o.w = (unsigned)f2bf(b.z) | ((unsigned)f2bf(b.w) << 16);
  const size_t off = ((size_t)(k >> 5) * 1024 + (size_t)g * 32 + (k & 31)) * 8;
  *(uint4*)(Ebs + off) = o;
  double s = (double)a.x * a.x + (double)a.y * a.y + (double)a.z * a.z +
             (double)a.w * a.w + (double)b.x * b.x + (double)b.y * b.y +
             (double)b.z * b.z + (double)b.w * b.w;
#pragma unroll
  for (int m = 1; m <= 16; m <<= 1) s += __shfl_xor(s, m, 64);
  if (g == 0) enorm[k] = (float)s;
}

// ---- fused bf16 MFMA score + argmin, split-K, no K-loop barriers ----
// Grid 512 x 256. Block (rowblk = b>>1, half = b&1): 64 rows x 4096 codes.
// Wave w owns 16-code groups gg = half*256 + w + 4*i, i = 0..63 (ascending).
__global__ __launch_bounds__(256, 2) void vq_score_argmin(
    const float* __restrict__ X, const unsigned short* __restrict__ Ebs,
    const float* __restrict__ enorm, unsigned long long* __restrict__ best64) {
  __shared__ float red_s[4][64];
  __shared__ int red_i[4][64];

  const int tid = threadIdx.x;
  const int wave = tid >> 6;
  const int lane = tid & 63;
  const int quad = lane >> 4;
  const int c15 = lane & 15;
  const int rowblk = blockIdx.x >> 1;
  const int half = blockIdx.x & 1;
  const int r0 = rowblk * 64;

  // Resident A fragments: af[t][kb], rows r0+t*16+c15, dims kb*32+quad*8..+8
  short8 af[4][8];
#pragma unroll
  for (int t = 0; t < 4; ++t) {
    const float* xr = X + (size_t)(r0 + t * 16 + c15) * VQ_D + quad * 8;
#pragma unroll
    for (int kb = 0; kb < 8; ++kb) {
      const float4 a = *(const float4*)(xr + kb * 32);
      const float4 b = *(const float4*)(xr + kb * 32 + 4);
      short8 f;
      f[0] = (short)f2bf(a.x); f[1] = (short)f2bf(a.y);
      f[2] = (short)f2bf(a.z); f[3] = (short)f2bf(a.w);
      f[4] = (short)f2bf(b.x); f[5] = (short)f2bf(b.y);
      f[6] = (short)f2bf(b.z); f[7] = (short)f2bf(b.w);
      af[t][kb] = f;
    }
  }

  float best_s[4][4];
  int best_i[4][4];
#pragma unroll
  for (int t = 0; t < 4; ++t)
#pragma unroll
    for (int r = 0; r < 4; ++r) { best_s[t][r] = 3.4e38f; best_i[t][r] = 0; }

  // B-frag shorts offset = (gg>>1)*8192 + quad*256 + ((gg&1)*16 + c15)*8 + kb*1024
  const unsigned short* ebase = Ebs + (size_t)quad * 256 + (size_t)c15 * 8;

#define LOADB(buf, en, gg)                                                   \
  {                                                                          \
    const unsigned short* bp =                                               \
        ebase + (size_t)((gg) >> 1) * 8192 + (size_t)((gg)&1) * 128;         \
    _Pragma("unroll") for (int kb = 0; kb < 8; ++kb)                         \
        buf[kb] = *(const short8*)(bp + kb * 1024);                          \
    en = enorm[(gg)*16 + c15];                                               \
  }

#define COMPUTE(buf, en, gg)                                                 \
  {                                                                          \
    f32x4 a0 = {0.f, 0.f, 0.f, 0.f}, a1 = {0.f, 0.f, 0.f, 0.f};             \
    f32x4 a2 = {0.f, 0.f, 0.f, 0.f}, a3 = {0.f, 0.f, 0.f, 0.f};             \
    _Pragma("unroll") for (int kb = 0; kb < 8; ++kb) {                       \
      a0 = __builtin_amdgcn_mfma_f32_16x16x32_bf16(af[0][kb], buf[kb], a0, 0, 0, 0); \
      a1 = __builtin_amdgcn_mfma_f32_16x16x32_bf16(af[1][kb], buf[kb], a1, 0, 0, 0); \
      a2 = __builtin_amdgcn_mfma_f32_16x16x32_bf16(af[2][kb], buf[kb], a2, 0, 0, 0); \
      a3 = __builtin_amdgcn_mfma_f32_16x16x32_bf16(af[3][kb], buf[kb], a3, 0, 0, 0); \
    }                                                                        \
    const int code = (gg)*16 + c15;                                          \
    _Pragma("unroll") for (int r = 0; r < 4; ++r) {                          \
      float s;                                                               \
      s = fmaf(a0[r], -2.0f, en);                                            \
      if (s < best_s[0][r]) { best_s[0][r] = s; best_i[0][r] = code; }       \
      s = fmaf(a1[r], -2.0f, en);                                            \
      if (s < best_s[1][r]) { best_s[1][r] = s; best_i[1][r] = code; }       \
      s = fmaf(a2[r], -2.0f, en);                                            \
      if (s < best_s[2][r]) { best_s[2][r] = s; best_i[2][r] = code; }       \
      s = fmaf(a3[r], -2.0f, en);                                            \
      if (s < best_s[3][r]) { best_s[3][r] = s; best_i[3][r] = code; }       \
    }                                                                        \
  }

  const int gbase = half * 256 + wave;
  short8 bb0[8], bb1[8];
  float en0, en1;
  LOADB(bb0, en0, gbase);
  for (int it = 0; it < 64; it += 2) {
    const int g0 = gbase + 4 * it;
    LOADB(bb1, en1, g0 + 4);
    COMPUTE(bb0, en0, g0);
    if (it + 2 < 64) LOADB(bb0, en0, g0 + 8);
    COMPUTE(bb1, en1, g0 + 4);
  }
#undef LOADB
#undef COMPUTE

  // reduce over the 16 code-lanes (c15), keep lowest index on ties
#pragma unroll
  for (int t = 0; t < 4; ++t)
#pragma unroll
    for (int r = 0; r < 4; ++r) {
      float s = best_s[t][r];
      int i = best_i[t][r];
#pragma unroll
      for (int m = 1; m <= 8; m <<= 1) {
        const float os = __shfl_xor(s, m, 64);
        const int oi = __shfl_xor(i, m, 64);
        if (os < s || (os == s && oi < i)) { s = os; i = oi; }
      }
      if (c15 == 0) {
        red_s[wave][t * 16 + quad * 4 + r] = s;
        red_i[wave][t * 16 + quad * 4 + r] = i;
      }
    }
  __syncthreads();

  if (tid < 64) {
    float bs = red_s[0][tid];
    int bi = red_i[0][tid];
#pragma unroll
    for (int w = 1; w < 4; ++w) {
      const float s = red_s[w][tid];
      const int i = red_i[w][tid];
      if (s < bs || (s == bs && i < bi)) { bs = s; bi = i; }
    }
    best64[(size_t)half * VQ_N + r0 + tid] =
        ((unsigned long long)orderable(bs) << 32) | (unsigned)bi;
  }
}

// ---- gather quantized (from f32 E) + loss; merges the two code-halves ----
// 512 blocks x 256. One row per wave per iteration; 512 f64 atomics total.
__global__ __launch_bounds__(256) void vq_gather_loss(
    const float* __restrict__ X, const float* __restrict__ E,
    const unsigned long long* __restrict__ best64, float* __restrict__ outq,
    double* __restrict__ loss_sum) {
  __shared__ double wsum[4];
  const int wid = threadIdx.x >> 6;
  const int lane = threadIdx.x & 63;
  const int gw = blockIdx.x * 4 + wid;  // 0..2047
  double acc = 0.0;
#pragma unroll 4
  for (int row = gw; row < VQ_N; row += 2048) {
    const unsigned long long p0 = best64[row];
    const unsigned long long p1 = best64[VQ_N + row];
    const unsigned long long p = (p1 < p0) ? p1 : p0;
    const int k = (int)(p & 0xFFFFFFFFu);
    const float4 q = *(const float4*)(E + (size_t)k * VQ_D + lane * 4);
    const float4 x = *(const float4*)(X + (size_t)row * VQ_D + lane * 4);
    *(float4*)(outq + (size_t)row * VQ_D + lane * 4) = q;
    const double dx = (double)q.x - x.x, dy = (double)q.y - x.y;
    const double dz = (double)q.z - x.z, dw = (double)q.w - x.w;
    acc += dx * dx + dy * dy + dz * dz + dw * dw;
  }
#pragma unroll
  for (int off = 32; off > 0; off >>= 1) acc += __shfl_down(acc, off, 64);
  if (lane == 0) wsum[wid] = acc;
  __syncthreads();
  if (threadIdx.x == 0)
    atomicAdd(loss_sum, wsum[0] + wsum[1] + wsum[2] + wsum[3]);
}

// ---- finalize: LDS histogram from best64 -> perplexity; loss ----
__global__ __launch_bounds__(256) void vq_finalize(
    const unsigned long long* __restrict__ best64,
    const double* __restrict__ loss_sum, float* __restrict__ out) {
  __shared__ int hist[VQ_K];      // 32 KB
  __shared__ double part[256];
  const int tx = threadIdx.x;
  for (int k = tx; k < VQ_K; k += 256) hist[k] = 0;
  __syncthreads();
  for (int row = tx; row < VQ_N; row += 256) {
    const unsigned long long p0 = best64[row];
    const unsigned long long p1 = best64[VQ_N + row];
    const unsigned long long p = (p1 < p0) ? p1 : p0;
    atomicAdd(&hist[(int)(p & 0xFFFFFFFFu)], 1);
  }
  __syncthreads();
  double s = 0.0;
  for (int k = tx; k < VQ_K; k += 256) {
    const int c = hist[k];
    if (c > 0) {
      const double pr = (double)c * (1.0 / (double)VQ_N);
      s += pr * log(pr + 1e-10);
    }
  }
  part[tx] = s;
  __syncthreads();
  for (int off = 128; off > 0; off >>= 1) {
    if (tx < off) part[tx] += part[tx + off];
    __syncthreads();
  }
  if (tx == 0) {
    out[(size_t)VQ_N * VQ_D] =
        (float)(1.25 * (*loss_sum) / ((double)VQ_N * (double)VQ_D));
    out[(size_t)VQ_N * VQ_D + 1] = (float)exp(-part[0]);
  }
}

extern "C" void kernel_launch(void* const* d_in, const int* in_sizes, int n_in,
                              void* d_out, int out_size, void* d_ws,
                              size_t ws_size, hipStream_t stream) {
  const float* X = (const float*)d_in[0];
  const float* E = (const float*)d_in[1];
  float* out = (float*)d_out;

  char* ws = (char*)d_ws;
  unsigned short* Ebs = (unsigned short*)ws;                 // 4 MB
  float* enorm = (float*)(ws + 4194304);                     // 32 KB
  double* loss_sum = (double*)(ws + 4227072);                // 64 B
  unsigned long long* best64 =
      (unsigned long long*)(ws + 4227136);                   // 256 KB

  vq_pack_e<<<1024, 256, 0, stream>>>(E, Ebs, enorm, loss_sum);
  vq_score_argmin<<<512, 256, 0, stream>>>(X, Ebs, enorm, best64);
  vq_gather_loss<<<512, 256, 0, stream>>>(X, E, best64, out, loss_sum);
  vq_finalize<<<1, 256, 0, stream>>>(best64, loss_sum, out);
}

// Round 5
// 192.692 us; speedup vs baseline: 1.1090x; 1.1090x over previous
//
#include <hip/hip_runtime.h>

// VectorQuantizer: x [16,1024,256] f32, E [8192,256] f32.
// Outputs concat: quantized_st (4194304 f32) | loss (1) | perplexity (1).
//
// Round 5: round-4 split-K structure, but __launch_bounds__(256,1).
// Round-4 post-mortem: the (256,2) bound capped unified regs at 256/wave and
// the allocator evicted the loop-invariant af[4][8] A-fragments from arch
// VGPRs (VGPR_Count 172->128), adding per-MFMA operand shuffles: per-wave
// MFMA busy fell 30%->12.5%. With (256,1) the same body compiles to ~172
// VGPRs (round-3 evidence); 172v + ~32a <= 256 still gives 2 waves/SIMD at
// grid 512 = 2 blocks/CU, now with clean register operands.

#define VQ_N 16384
#define VQ_D 256
#define VQ_K 8192

typedef __attribute__((ext_vector_type(8))) short short8;   // 8 bf16
typedef __attribute__((ext_vector_type(4))) float f32x4;

__device__ inline unsigned short f2bf(float f) {  // RNE f32 -> bf16 bits
  unsigned int u = __float_as_uint(f);
  return (unsigned short)((u + 0x7fffu + ((u >> 16) & 1u)) >> 16);
}

__device__ inline unsigned int orderable(float s) {
  const unsigned int u = __float_as_uint(s);
  return ((int)u < 0) ? ~u : (u | 0x80000000u);
}

// ---- pack E -> bf16 swizzled + enorm (fused); also zeroes loss_sum ----
// Swizzle: 16B block at ((c*32 + g)*32 + kl)*16 bytes; c=k>>5, g=dim/8, kl=k&31.
__global__ __launch_bounds__(256) void vq_pack_e(
    const float* __restrict__ E, unsigned short* __restrict__ Ebs,
    float* __restrict__ enorm, double* __restrict__ loss_sum) {
  const int gid = blockIdx.x * 256 + threadIdx.x;  // 0..262143
  if (gid == 0) *loss_sum = 0.0;
  const int k = gid >> 5;
  const int g = gid & 31;
  const float* src = E + (size_t)k * VQ_D + g * 8;
  const float4 a = *(const float4*)src;
  const float4 b = *(const float4*)(src + 4);
  uint4 o;
  o.x = (unsigned)f2bf(a.x) | ((unsigned)f2bf(a.y) << 16);
  o.y = (unsigned)f2bf(a.z) | ((unsigned)f2bf(a.w) << 16);
  o.z = (unsigned)f2bf(b.x) | ((unsigned)f2bf(b.y) << 16);
  o.w = (unsigned)f2bf(b.z) | ((unsigned)f2bf(b.w) << 16);
  const size_t off = ((size_t)(k >> 5) * 1024 + (size_t)g * 32 + (k & 31)) * 8;
  *(uint4*)(Ebs + off) = o;
  double s = (double)a.x * a.x + (double)a.y * a.y + (double)a.z * a.z +
             (double)a.w * a.w + (double)b.x * b.x + (double)b.y * b.y +
             (double)b.z * b.z + (double)b.w * b.w;
#pragma unroll
  for (int m = 1; m <= 16; m <<= 1) s += __shfl_xor(s, m, 64);
  if (g == 0) enorm[k] = (float)s;
}

// ---- fused bf16 MFMA score + argmin, split-K, no K-loop barriers ----
// Grid 512 x 256. Block (rowblk = b>>1, half = b&1): 64 rows x 4096 codes.
// Wave w owns 16-code groups gg = half*256 + w + 4*i, i = 0..63 (ascending).
__global__ __launch_bounds__(256, 1) void vq_score_argmin(
    const float* __restrict__ X, const unsigned short* __restrict__ Ebs,
    const float* __restrict__ enorm, unsigned long long* __restrict__ best64) {
  __shared__ float red_s[4][64];
  __shared__ int red_i[4][64];

  const int tid = threadIdx.x;
  const int wave = tid >> 6;
  const int lane = tid & 63;
  const int quad = lane >> 4;
  const int c15 = lane & 15;
  const int rowblk = blockIdx.x >> 1;
  const int half = blockIdx.x & 1;
  const int r0 = rowblk * 64;

  // Resident A fragments: af[t][kb], rows r0+t*16+c15, dims kb*32+quad*8..+8
  short8 af[4][8];
#pragma unroll
  for (int t = 0; t < 4; ++t) {
    const float* xr = X + (size_t)(r0 + t * 16 + c15) * VQ_D + quad * 8;
#pragma unroll
    for (int kb = 0; kb < 8; ++kb) {
      const float4 a = *(const float4*)(xr + kb * 32);
      const float4 b = *(const float4*)(xr + kb * 32 + 4);
      short8 f;
      f[0] = (short)f2bf(a.x); f[1] = (short)f2bf(a.y);
      f[2] = (short)f2bf(a.z); f[3] = (short)f2bf(a.w);
      f[4] = (short)f2bf(b.x); f[5] = (short)f2bf(b.y);
      f[6] = (short)f2bf(b.z); f[7] = (short)f2bf(b.w);
      af[t][kb] = f;
    }
  }

  float best_s[4][4];
  int best_i[4][4];
#pragma unroll
  for (int t = 0; t < 4; ++t)
#pragma unroll
    for (int r = 0; r < 4; ++r) { best_s[t][r] = 3.4e38f; best_i[t][r] = 0; }

  // B-frag shorts offset = (gg>>1)*8192 + quad*256 + ((gg&1)*16 + c15)*8 + kb*1024
  const unsigned short* ebase = Ebs + (size_t)quad * 256 + (size_t)c15 * 8;

#define LOADB(buf, en, gg)                                                   \
  {                                                                          \
    const unsigned short* bp =                                               \
        ebase + (size_t)((gg) >> 1) * 8192 + (size_t)((gg)&1) * 128;         \
    _Pragma("unroll") for (int kb = 0; kb < 8; ++kb)                         \
        buf[kb] = *(const short8*)(bp + kb * 1024);                          \
    en = enorm[(gg)*16 + c15];                                               \
  }

#define COMPUTE(buf, en, gg)                                                 \
  {                                                                          \
    f32x4 a0 = {0.f, 0.f, 0.f, 0.f}, a1 = {0.f, 0.f, 0.f, 0.f};             \
    f32x4 a2 = {0.f, 0.f, 0.f, 0.f}, a3 = {0.f, 0.f, 0.f, 0.f};             \
    _Pragma("unroll") for (int kb = 0; kb < 8; ++kb) {                       \
      a0 = __builtin_amdgcn_mfma_f32_16x16x32_bf16(af[0][kb], buf[kb], a0, 0, 0, 0); \
      a1 = __builtin_amdgcn_mfma_f32_16x16x32_bf16(af[1][kb], buf[kb], a1, 0, 0, 0); \
      a2 = __builtin_amdgcn_mfma_f32_16x16x32_bf16(af[2][kb], buf[kb], a2, 0, 0, 0); \
      a3 = __builtin_amdgcn_mfma_f32_16x16x32_bf16(af[3][kb], buf[kb], a3, 0, 0, 0); \
    }                                                                        \
    const int code = (gg)*16 + c15;                                          \
    _Pragma("unroll") for (int r = 0; r < 4; ++r) {                          \
      float s;                                                               \
      s = fmaf(a0[r], -2.0f, en);                                            \
      if (s < best_s[0][r]) { best_s[0][r] = s; best_i[0][r] = code; }       \
      s = fmaf(a1[r], -2.0f, en);                                            \
      if (s < best_s[1][r]) { best_s[1][r] = s; best_i[1][r] = code; }       \
      s = fmaf(a2[r], -2.0f, en);                                            \
      if (s < best_s[2][r]) { best_s[2][r] = s; best_i[2][r] = code; }       \
      s = fmaf(a3[r], -2.0f, en);                                            \
      if (s < best_s[3][r]) { best_s[3][r] = s; best_i[3][r] = code; }       \
    }                                                                        \
  }

  const int gbase = half * 256 + wave;
  short8 bb0[8], bb1[8];
  float en0, en1;
  LOADB(bb0, en0, gbase);
  for (int it = 0; it < 64; it += 2) {
    const int g0 = gbase + 4 * it;
    LOADB(bb1, en1, g0 + 4);
    COMPUTE(bb0, en0, g0);
    if (it + 2 < 64) LOADB(bb0, en0, g0 + 8);
    COMPUTE(bb1, en1, g0 + 4);
  }
#undef LOADB
#undef COMPUTE

  // reduce over the 16 code-lanes (c15), keep lowest index on ties
#pragma unroll
  for (int t = 0; t < 4; ++t)
#pragma unroll
    for (int r = 0; r < 4; ++r) {
      float s = best_s[t][r];
      int i = best_i[t][r];
#pragma unroll
      for (int m = 1; m <= 8; m <<= 1) {
        const float os = __shfl_xor(s, m, 64);
        const int oi = __shfl_xor(i, m, 64);
        if (os < s || (os == s && oi < i)) { s = os; i = oi; }
      }
      if (c15 == 0) {
        red_s[wave][t * 16 + quad * 4 + r] = s;
        red_i[wave][t * 16 + quad * 4 + r] = i;
      }
    }
  __syncthreads();

  if (tid < 64) {
    float bs = red_s[0][tid];
    int bi = red_i[0][tid];
#pragma unroll
    for (int w = 1; w < 4; ++w) {
      const float s = red_s[w][tid];
      const int i = red_i[w][tid];
      if (s < bs || (s == bs && i < bi)) { bs = s; bi = i; }
    }
    best64[(size_t)half * VQ_N + r0 + tid] =
        ((unsigned long long)orderable(bs) << 32) | (unsigned)bi;
  }
}

// ---- gather quantized (from f32 E) + loss; merges the two code-halves ----
// 512 blocks x 256. One row per wave per iteration; 512 f64 atomics total.
__global__ __launch_bounds__(256) void vq_gather_loss(
    const float* __restrict__ X, const float* __restrict__ E,
    const unsigned long long* __restrict__ best64, float* __restrict__ outq,
    double* __restrict__ loss_sum) {
  __shared__ double wsum[4];
  const int wid = threadIdx.x >> 6;
  const int lane = threadIdx.x & 63;
  const int gw = blockIdx.x * 4 + wid;  // 0..2047
  double acc = 0.0;
#pragma unroll 4
  for (int row = gw; row < VQ_N; row += 2048) {
    const unsigned long long p0 = best64[row];
    const unsigned long long p1 = best64[VQ_N + row];
    const unsigned long long p = (p1 < p0) ? p1 : p0;
    const int k = (int)(p & 0xFFFFFFFFu);
    const float4 q = *(const float4*)(E + (size_t)k * VQ_D + lane * 4);
    const float4 x = *(const float4*)(X + (size_t)row * VQ_D + lane * 4);
    *(float4*)(outq + (size_t)row * VQ_D + lane * 4) = q;
    const double dx = (double)q.x - x.x, dy = (double)q.y - x.y;
    const double dz = (double)q.z - x.z, dw = (double)q.w - x.w;
    acc += dx * dx + dy * dy + dz * dz + dw * dw;
  }
#pragma unroll
  for (int off = 32; off > 0; off >>= 1) acc += __shfl_down(acc, off, 64);
  if (lane == 0) wsum[wid] = acc;
  __syncthreads();
  if (threadIdx.x == 0)
    atomicAdd(loss_sum, wsum[0] + wsum[1] + wsum[2] + wsum[3]);
}

// ---- finalize: LDS histogram from best64 -> perplexity; loss ----
__global__ __launch_bounds__(1024) void vq_finalize(
    const unsigned long long* __restrict__ best64,
    const double* __restrict__ loss_sum, float* __restrict__ out) {
  __shared__ int hist[VQ_K];      // 32 KB
  __shared__ double part[1024];
  const int tx = threadIdx.x;
  for (int k = tx; k < VQ_K; k += 1024) hist[k] = 0;
  __syncthreads();
  for (int row = tx; row < VQ_N; row += 1024) {
    const unsigned long long p0 = best64[row];
    const unsigned long long p1 = best64[VQ_N + row];
    const unsigned long long p = (p1 < p0) ? p1 : p0;
    atomicAdd(&hist[(int)(p & 0xFFFFFFFFu)], 1);
  }
  __syncthreads();
  double s = 0.0;
  for (int k = tx; k < VQ_K; k += 1024) {
    const int c = hist[k];
    if (c > 0) {
      const double pr = (double)c * (1.0 / (double)VQ_N);
      s += pr * log(pr + 1e-10);
    }
  }
  part[tx] = s;
  __syncthreads();
  for (int off = 512; off > 0; off >>= 1) {
    if (tx < off) part[tx] += part[tx + off];
    __syncthreads();
  }
  if (tx == 0) {
    out[(size_t)VQ_N * VQ_D] =
        (float)(1.25 * (*loss_sum) / ((double)VQ_N * (double)VQ_D));
    out[(size_t)VQ_N * VQ_D + 1] = (float)exp(-part[0]);
  }
}

extern "C" void kernel_launch(void* const* d_in, const int* in_sizes, int n_in,
                              void* d_out, int out_size, void* d_ws,
                              size_t ws_size, hipStream_t stream) {
  const float* X = (const float*)d_in[0];
  const float* E = (const float*)d_in[1];
  float* out = (float*)d_out;

  char* ws = (char*)d_ws;
  unsigned short* Ebs = (unsigned short*)ws;                 // 4 MB
  float* enorm = (float*)(ws + 4194304);                     // 32 KB
  double* loss_sum = (double*)(ws + 4227072);                // 64 B
  unsigned long long* best64 =
      (unsigned long long*)(ws + 4227136);                   // 256 KB

  vq_pack_e<<<1024, 256, 0, stream>>>(E, Ebs, enorm, loss_sum);
  vq_score_argmin<<<512, 256, 0, stream>>>(X, Ebs, enorm, best64);
  vq_gather_loss<<<512, 256, 0, stream>>>(X, E, best64, out, loss_sum);
  vq_finalize<<<1, 1024, 0, stream>>>(best64, loss_sum, out);
}